// Round 3
// baseline (454.826 us; speedup 1.0000x reference)
//
#include <hip/hip_runtime.h>

// Problem constants (match reference setup_inputs)
#define BATCH 32768
#define LMAX  24
#define MOUT  10
#define DIM   300
#define VOCAB 36
#define D4    (DIM / 4)                  // 75 float4 per row
#define NROW  (BATCH * MOUT)             // 327,680 output rows
#define N4    (NROW * D4)                // 24,576,000 float4 outputs
#define PAD_OFF (VOCAB * DIM)            // float offset of pad row inside LDS
#define LDSF  (VOCAB * DIM + DIM)        // 11,100 floats = 44.4 KB

// ---------------------------------------------------------------------------
// Fused single-pass kernel, wave-uniform descriptor computation.
//
// Key fact: a wave's 64 contiguous float4 elements span at most TWO output
// rows (one row = 75 float4 > 64). So per wave-iteration we need at most two
// descriptors {lo_off, hi_off, w}. Compute BOTH on wave-uniform values
// (readfirstlane -> SALU + s_load chains, uniform s_cbranch branches, zero
// divergence), then each lane cndmask-selects its row's descriptor.
// This removes round 1's desc pass (8 us launch + 10.5 MB round-trip) without
// round 2's per-element descriptor cost (+50 us).
//
// NOTE: the harness's 1.536 GB workspace re-poison fill is UNCONDITIONAL
// (round 2 proved: no ws use, fill still present). d_ws is ignored here; the
// ~319 us of poison fills are a fixed cost we cannot affect.
// ---------------------------------------------------------------------------
#define TPB   512
#define NBLK  750
#define NTHR  (TPB * NBLK)               // 384,000 threads
#define ITERS (N4 / NTHR)                // 64 elements per thread, exact

// Descriptor for row r, computed on wave-uniform r (all branches uniform).
__device__ __forceinline__ void desc_uniform(const int* __restrict__ tokens,
                                             const int* __restrict__ lengths,
                                             int r, int& lo_off, int& hi_off,
                                             float& w)
{
    const int b = r / MOUT;              // SALU (uniform)
    const int i = r - b * MOUT;
    const int L = lengths[b];            // s_load (uniform addr)
    const int* trow = tokens + b * LMAX;
    if (L < MOUT) {                      // uniform branch: s_cbranch, no divergence
        const int off = (i < L) ? trow[i] * DIM : PAD_OFF;
        lo_off = off; hi_off = off; w = 0.0f;
    } else {
        // exact reference arithmetic: pos = (float)i * (float)(L-1) / 9.0f
        const float pos = ((float)i * (float)(L - 1)) / (float)(MOUT - 1);
        int lo = (int)floorf(pos);
        w = pos - (float)lo;
        int hi = min(lo + 1, L - 1);
        // force back to SGPR so the token loads stay scalar
        lo = __builtin_amdgcn_readfirstlane(lo);
        hi = __builtin_amdgcn_readfirstlane(hi);
        lo_off = trow[lo] * DIM;
        hi_off = trow[hi] * DIM;
    }
}

__global__ __launch_bounds__(TPB) void emb_fused2_kernel(
    const float* __restrict__ emb,      // [VOCAB, DIM]
    const float* __restrict__ pad,      // [1, DIM]
    const int*   __restrict__ tokens,   // [BATCH, LMAX]
    const int*   __restrict__ lengths,  // [BATCH]
    float4*      __restrict__ out)      // [N4]
{
    __shared__ float lds[LDSF];
    {
        const float4* e4 = (const float4*)emb;
        float4* l4 = (float4*)lds;
        for (int i = threadIdx.x; i < VOCAB * D4; i += TPB) l4[i] = e4[i];
        const float4* p4 = (const float4*)pad;
        for (int i = threadIdx.x; i < D4; i += TPB) l4[VOCAB * D4 + i] = p4[i];
    }
    __syncthreads();

    const int gid = blockIdx.x * TPB + threadIdx.x;

#pragma unroll 4
    for (int it = 0; it < ITERS; ++it) {
        const int e = it * NTHR + gid;   // lanes contiguous within a wave
        const int r = e / D4;            // magic-mul div by 75
        const int j = e - r * D4;

        // first lane's row; wave spans rows {r0, r0+1} only
        const int r0 = __builtin_amdgcn_readfirstlane(r);
        const int r1 = min(r0 + 1, NROW - 1);   // guard last partial wave-span

        int lo0, hi0, lo1, hi1;
        float w0, w1;
        desc_uniform(tokens, lengths, r0, lo0, hi0, w0);
        desc_uniform(tokens, lengths, r1, lo1, hi1, w1);

        // per-lane select between the two uniform descriptors (3 cndmask)
        const bool second = (r != r0);
        const int   lo = second ? lo1 : lo0;
        const int   hi = second ? hi1 : hi0;
        const float w  = second ? w1  : w0;

        const float4 a = *(const float4*)&lds[lo + 4 * j];
        const float4 b = *(const float4*)&lds[hi + 4 * j];
        const float u = 1.0f - w;

        float4 v;
        v.x = a.x * u + b.x * w;
        v.y = a.y * u + b.y * w;
        v.z = a.z * u + b.z * w;
        v.w = a.w * u + b.w * w;

        out[e] = v;
    }
}

extern "C" void kernel_launch(void* const* d_in, const int* in_sizes, int n_in,
                              void* d_out, int out_size, void* d_ws, size_t ws_size,
                              hipStream_t stream) {
    const float* emb     = (const float*)d_in[0];
    const float* pad     = (const float*)d_in[1];
    const int*   tokens  = (const int*)d_in[2];
    const int*   lengths = (const int*)d_in[3];
    float4* out = (float4*)d_out;

    (void)d_ws; (void)ws_size;  // ws poison is unconditional; not using ws

    emb_fused2_kernel<<<NBLK, TPB, 0, stream>>>(emb, pad, tokens, lengths, out);
}

// Round 6
// 399.293 us; speedup vs baseline: 1.1391x; 1.1391x over previous
//
#include <hip/hip_runtime.h>

// Problem constants (match reference setup_inputs)
#define BATCH 32768
#define LMAX  24
#define MOUT  10
#define DIM   300
#define VOCAB 36
#define D4    (DIM / 4)                  // 75 float4 per row
#define NROW  (BATCH * MOUT)             // 327,680 output rows
#define N4    (NROW * D4)                // 24,576,000 float4 outputs
#define PAD_OFF (VOCAB * DIM)            // float offset of pad row inside LDS
#define TABF  (VOCAB * DIM + DIM)        // 11,100 floats = 44.4 KB table

// Native 4-float vector for __builtin_nontemporal_store (HIP's float4 is a
// class type the builtin rejects; this alias is layout-identical).
typedef float nfloat4 __attribute__((ext_vector_type(4)));

// ---------------------------------------------------------------------------
// One-pass kernel, per-block descriptor precompute in LDS.
//
// Timing decomposition (R1-R3 consistent): 319 us of harness poison fills are
// unconditional and untouchable; our controllable part was 85 us in the best
// (two-pass) version vs a ~63 us store-BW floor. This version removes the
// desc kernel launch (+8 us) and the desc HBM round-trip:
//   - block-contiguous mapping: block owns 32,768 consecutive float4
//     -> spans <= 438 output rows
//   - desc phase: one desc per thread, plain vector path (R1 desc_kernel
//     body — NO scalar/readfirstlane tricks, R3 proved those serialize),
//     written to 7 KB LDS
//   - main loop: R1's 4x-unrolled branch-free gather+lerp, desc read as
//     ds_read_b128 (wave touches <= 2 rows -> broadcast, conflict-free)
//   - nontemporal stores (write-once output, no L2 allocate)
// LDS: 44.4 KB table + 7 KB desc = 51.4 KB -> 3 blocks/CU = 24 waves/CU.
// ---------------------------------------------------------------------------
#define TPB   512
#define NBLK  750
#define EPB   (N4 / NBLK)                // 32,768 float4 per block (exact)
#define ITERS (EPB / TPB)                // 64 iterations per thread
#define MAXD  440                        // >= max rows straddled by a block

__global__ __launch_bounds__(TPB) void emb_onepass_kernel(
    const float* __restrict__ emb,      // [VOCAB, DIM]
    const float* __restrict__ pad,      // [1, DIM]
    const int*   __restrict__ tokens,   // [BATCH, LMAX]
    const int*   __restrict__ lengths,  // [BATCH]
    float*       __restrict__ out)      // [N4 * 4] floats
{
    __shared__ float tab[TABF];
    __shared__ int4  dsc[MAXD];

    // --- stage embedding + pad tables ---
    {
        const float4* e4 = (const float4*)emb;
        float4* t4 = (float4*)tab;
        for (int i = threadIdx.x; i < VOCAB * D4; i += TPB) t4[i] = e4[i];
        const float4* p4 = (const float4*)pad;
        for (int i = threadIdx.x; i < D4; i += TPB) t4[VOCAB * D4 + i] = p4[i];
    }

    // --- per-block descriptor precompute (vector path, one row per thread) ---
    const int eBase = blockIdx.x * EPB;
    const int rBase = eBase / D4;
    const int rEnd  = (eBase + EPB - 1) / D4;
    const int nR    = rEnd - rBase + 1;          // <= 438
    for (int idx = threadIdx.x; idx < nR; idx += TPB) {
        const int r = rBase + idx;
        const int b = r / MOUT;                  // magic-mul div
        const int i = r - b * MOUT;
        const int L = lengths[b];
        int lo_off, hi_off;
        float w;
        if (L < MOUT) {
            const int off = (i < L) ? tokens[b * LMAX + i] * DIM : PAD_OFF;
            lo_off = off; hi_off = off; w = 0.0f;
        } else {
            // exact reference arithmetic: pos = (float)i*(float)(L-1)/9.0f
            const float pos = ((float)i * (float)(L - 1)) / (float)(MOUT - 1);
            const int   lo  = (int)floorf(pos);
            const int   hi  = min(lo + 1, L - 1);
            w = pos - (float)lo;
            lo_off = tokens[b * LMAX + lo] * DIM;
            hi_off = tokens[b * LMAX + hi] * DIM;
        }
        dsc[idx] = make_int4(lo_off, hi_off, __float_as_int(w), 0);
    }
    __syncthreads();

    // --- main loop: branch-free gather + lerp, 4x unrolled ---
    nfloat4* out4 = (nfloat4*)out;
    int e = eBase + threadIdx.x;
    for (int g = 0; g < ITERS / 4; ++g) {
        const int e0 = e, e1 = e + TPB, e2 = e + 2 * TPB, e3 = e + 3 * TPB;

        const int r0 = e0 / D4, r1 = e1 / D4, r2 = e2 / D4, r3 = e3 / D4;
        const int j0 = e0 - r0 * D4, j1 = e1 - r1 * D4;
        const int j2 = e2 - r2 * D4, j3 = e3 - r3 * D4;

        const int4 d0 = dsc[r0 - rBase];
        const int4 d1 = dsc[r1 - rBase];
        const int4 d2 = dsc[r2 - rBase];
        const int4 d3 = dsc[r3 - rBase];

        const float4 a0 = *(const float4*)&tab[d0.x + 4 * j0];
        const float4 b0 = *(const float4*)&tab[d0.y + 4 * j0];
        const float4 a1 = *(const float4*)&tab[d1.x + 4 * j1];
        const float4 b1 = *(const float4*)&tab[d1.y + 4 * j1];
        const float4 a2 = *(const float4*)&tab[d2.x + 4 * j2];
        const float4 b2 = *(const float4*)&tab[d2.y + 4 * j2];
        const float4 a3 = *(const float4*)&tab[d3.x + 4 * j3];
        const float4 b3 = *(const float4*)&tab[d3.y + 4 * j3];

        const float w0 = __int_as_float(d0.z), u0 = 1.0f - w0;
        const float w1 = __int_as_float(d1.z), u1 = 1.0f - w1;
        const float w2 = __int_as_float(d2.z), u2 = 1.0f - w2;
        const float w3 = __int_as_float(d3.z), u3 = 1.0f - w3;

        nfloat4 v0, v1, v2, v3;
        v0.x = a0.x * u0 + b0.x * w0; v0.y = a0.y * u0 + b0.y * w0;
        v0.z = a0.z * u0 + b0.z * w0; v0.w = a0.w * u0 + b0.w * w0;
        v1.x = a1.x * u1 + b1.x * w1; v1.y = a1.y * u1 + b1.y * w1;
        v1.z = a1.z * u1 + b1.z * w1; v1.w = a1.w * u1 + b1.w * w1;
        v2.x = a2.x * u2 + b2.x * w2; v2.y = a2.y * u2 + b2.y * w2;
        v2.z = a2.z * u2 + b2.z * w2; v2.w = a2.w * u2 + b2.w * w2;
        v3.x = a3.x * u3 + b3.x * w3; v3.y = a3.y * u3 + b3.y * w3;
        v3.z = a3.z * u3 + b3.z * w3; v3.w = a3.w * u3 + b3.w * w3;

        __builtin_nontemporal_store(v0, out4 + e0);
        __builtin_nontemporal_store(v1, out4 + e1);
        __builtin_nontemporal_store(v2, out4 + e2);
        __builtin_nontemporal_store(v3, out4 + e3);

        e += 4 * TPB;
    }
}

extern "C" void kernel_launch(void* const* d_in, const int* in_sizes, int n_in,
                              void* d_out, int out_size, void* d_ws, size_t ws_size,
                              hipStream_t stream) {
    const float* emb     = (const float*)d_in[0];
    const float* pad     = (const float*)d_in[1];
    const int*   tokens  = (const int*)d_in[2];
    const int*   lengths = (const int*)d_in[3];
    float* out = (float*)d_out;

    (void)d_ws; (void)ws_size;  // poison fills are unconditional; ws unused

    emb_onepass_kernel<<<NBLK, TPB, 0, stream>>>(emb, pad, tokens, lengths, out);
}

// Round 7
// 397.794 us; speedup vs baseline: 1.1434x; 1.0038x over previous
//
#include <hip/hip_runtime.h>

// Problem constants (match reference setup_inputs)
#define BATCH 32768
#define LMAX  24
#define MOUT  10
#define DIM   300
#define VOCAB 36
#define D4    (DIM / 4)                  // 75 float4 per row
#define NROW  (BATCH * MOUT)             // 327,680 output rows
#define N4    (NROW * D4)                // 24,576,000 float4 outputs
#define PAD_OFF (VOCAB * DIM)            // float offset of pad row inside LDS
#define TABF  (VOCAB * DIM + DIM)        // 11,100 floats = 44.4 KB table

// ---------------------------------------------------------------------------
// One-pass kernel, per-block descriptor precompute in LDS.
// R6 A/B: REGULAR stores (this round) vs nontemporal (R6: 399.3 us total,
// ~82 us kernel). Single-variable experiment — everything else identical.
//
// Fixed costs (R1-R6 consistent): ~317 us of unconditional harness poison
// fills; floor for our kernel ~63 us (393 MB at the fills' measured
// 6.3 TB/s write BW). R6 kernel ~82 us; the store path is the last
// unmeasured variable.
// LDS: 44.4 KB table + 7 KB desc = 51.4 KB -> 3 blocks/CU, fully resident
// grid (750 blocks <= 256 CU x 3).
// ---------------------------------------------------------------------------
#define TPB   512
#define NBLK  750
#define EPB   (N4 / NBLK)                // 32,768 float4 per block (exact)
#define ITERS (EPB / TPB)                // 64 iterations per thread
#define MAXD  440                        // >= max rows straddled by a block

__global__ __launch_bounds__(TPB) void emb_onepass_kernel(
    const float* __restrict__ emb,      // [VOCAB, DIM]
    const float* __restrict__ pad,      // [1, DIM]
    const int*   __restrict__ tokens,   // [BATCH, LMAX]
    const int*   __restrict__ lengths,  // [BATCH]
    float4*      __restrict__ out)      // [N4]
{
    __shared__ float tab[TABF];
    __shared__ int4  dsc[MAXD];

    // --- stage embedding + pad tables ---
    {
        const float4* e4 = (const float4*)emb;
        float4* t4 = (float4*)tab;
        for (int i = threadIdx.x; i < VOCAB * D4; i += TPB) t4[i] = e4[i];
        const float4* p4 = (const float4*)pad;
        for (int i = threadIdx.x; i < D4; i += TPB) t4[VOCAB * D4 + i] = p4[i];
    }

    // --- per-block descriptor precompute (vector path, one row per thread) ---
    const int eBase = blockIdx.x * EPB;
    const int rBase = eBase / D4;
    const int rEnd  = (eBase + EPB - 1) / D4;
    const int nR    = rEnd - rBase + 1;          // <= 438
    for (int idx = threadIdx.x; idx < nR; idx += TPB) {
        const int r = rBase + idx;
        const int b = r / MOUT;                  // magic-mul div
        const int i = r - b * MOUT;
        const int L = lengths[b];
        int lo_off, hi_off;
        float w;
        if (L < MOUT) {
            const int off = (i < L) ? tokens[b * LMAX + i] * DIM : PAD_OFF;
            lo_off = off; hi_off = off; w = 0.0f;
        } else {
            // exact reference arithmetic: pos = (float)i*(float)(L-1)/9.0f
            const float pos = ((float)i * (float)(L - 1)) / (float)(MOUT - 1);
            const int   lo  = (int)floorf(pos);
            const int   hi  = min(lo + 1, L - 1);
            w = pos - (float)lo;
            lo_off = tokens[b * LMAX + lo] * DIM;
            hi_off = tokens[b * LMAX + hi] * DIM;
        }
        dsc[idx] = make_int4(lo_off, hi_off, __float_as_int(w), 0);
    }
    __syncthreads();

    // --- main loop: branch-free gather + lerp, 4x unrolled ---
    int e = eBase + threadIdx.x;
    for (int g = 0; g < ITERS / 4; ++g) {
        const int e0 = e, e1 = e + TPB, e2 = e + 2 * TPB, e3 = e + 3 * TPB;

        const int r0 = e0 / D4, r1 = e1 / D4, r2 = e2 / D4, r3 = e3 / D4;
        const int j0 = e0 - r0 * D4, j1 = e1 - r1 * D4;
        const int j2 = e2 - r2 * D4, j3 = e3 - r3 * D4;

        const int4 d0 = dsc[r0 - rBase];
        const int4 d1 = dsc[r1 - rBase];
        const int4 d2 = dsc[r2 - rBase];
        const int4 d3 = dsc[r3 - rBase];

        const float4 a0 = *(const float4*)&tab[d0.x + 4 * j0];
        const float4 b0 = *(const float4*)&tab[d0.y + 4 * j0];
        const float4 a1 = *(const float4*)&tab[d1.x + 4 * j1];
        const float4 b1 = *(const float4*)&tab[d1.y + 4 * j1];
        const float4 a2 = *(const float4*)&tab[d2.x + 4 * j2];
        const float4 b2 = *(const float4*)&tab[d2.y + 4 * j2];
        const float4 a3 = *(const float4*)&tab[d3.x + 4 * j3];
        const float4 b3 = *(const float4*)&tab[d3.y + 4 * j3];

        const float w0 = __int_as_float(d0.z), u0 = 1.0f - w0;
        const float w1 = __int_as_float(d1.z), u1 = 1.0f - w1;
        const float w2 = __int_as_float(d2.z), u2 = 1.0f - w2;
        const float w3 = __int_as_float(d3.z), u3 = 1.0f - w3;

        float4 v0, v1, v2, v3;
        v0.x = a0.x * u0 + b0.x * w0; v0.y = a0.y * u0 + b0.y * w0;
        v0.z = a0.z * u0 + b0.z * w0; v0.w = a0.w * u0 + b0.w * w0;
        v1.x = a1.x * u1 + b1.x * w1; v1.y = a1.y * u1 + b1.y * w1;
        v1.z = a1.z * u1 + b1.z * w1; v1.w = a1.w * u1 + b1.w * w1;
        v2.x = a2.x * u2 + b2.x * w2; v2.y = a2.y * u2 + b2.y * w2;
        v2.z = a2.z * u2 + b2.z * w2; v2.w = a2.w * u2 + b2.w * w2;
        v3.x = a3.x * u3 + b3.x * w3; v3.y = a3.y * u3 + b3.y * w3;
        v3.z = a3.z * u3 + b3.z * w3; v3.w = a3.w * u3 + b3.w * w3;

        out[e0] = v0;
        out[e1] = v1;
        out[e2] = v2;
        out[e3] = v3;

        e += 4 * TPB;
    }
}

extern "C" void kernel_launch(void* const* d_in, const int* in_sizes, int n_in,
                              void* d_out, int out_size, void* d_ws, size_t ws_size,
                              hipStream_t stream) {
    const float* emb     = (const float*)d_in[0];
    const float* pad     = (const float*)d_in[1];
    const int*   tokens  = (const int*)d_in[2];
    const int*   lengths = (const int*)d_in[3];
    float4* out = (float4*)d_out;

    (void)d_ws; (void)ws_size;  // poison fills are unconditional; ws unused

    emb_onepass_kernel<<<NBLK, TPB, 0, stream>>>(emb, pad, tokens, lengths, out);
}